// Round 1
// baseline (172.191 us; speedup 1.0000x reference)
//
#include <hip/hip_runtime.h>

#define NPTS 768
#define CCH  128
#define NM4  36    // 35 deg<=4 monomials in (d,u,v) + 1 pad
#define NM2  10    // deg<=2 monomials
#define TILE 128
#define NCHUNK 6   // one 128-tile of n per block
#define PAIR (NPTS*CCH)
#define NACC 384   // apart accumulator size (3 x 128)
#define FINB 96    // k_fin grid
#define LOG2E 1.4426950408889634f
#define NQW  (NPTS*8*CCH)   // u32 words per split plane: 768 m x 8 k-pairs x 128 c

typedef __attribute__((ext_vector_type(8))) short bf16x8;   // 8 bf16 in 4 VGPRs
typedef __attribute__((ext_vector_type(16))) float f32x16;  // MFMA 32x32 acc
union Frag { unsigned int u[4]; bf16x8 h; };

__device__ __forceinline__ float fast_exp2(float x) {
  return __builtin_amdgcn_exp2f(x);   // v_exp_f32 (base-2)
}

// Truncation-based 3-way bf16 split: x = h0 + h1 + h2 + eps, |eps| <= 2^-27 |x|.
// (mask-truncation keeps each residual subtraction exact in fp32)
__device__ __forceinline__ void split3(float x, unsigned int& h0,
                                       unsigned int& h1, unsigned int& h2) {
  const unsigned int b0 = __float_as_uint(x);
  h0 = b0 >> 16;
  const float r1 = x - __uint_as_float(b0 & 0xFFFF0000u);
  const unsigned int b1 = __float_as_uint(r1);
  h1 = b1 >> 16;
  const float r2 = r1 - __uint_as_float(b1 & 0xFFFF0000u);
  h2 = __float_as_uint(r2) >> 16;
}

// ---- monomial index helpers ------------------------------------------------
// (a,b,c) = (deg d, deg u, deg v), a outermost.
__device__ __forceinline__ int t4i(int a, int b, int c) {
  int t = 0;
  for (int aa = 0; aa < a; ++aa) t += (5 - aa) * (6 - aa) / 2;
  for (int bb = 0; bb < b; ++bb) t += (5 - a - bb);
  return t + c;
}
__device__ __forceinline__ int t2i(int a, int b, int c) {
  int t = 0;
  for (int aa = 0; aa < a; ++aa) t += (3 - aa) * (4 - aa) / 2;
  for (int bb = 0; bb < b; ++bb) t += (3 - a - bb);
  return t + c;
}

// ---------------------------------------------------------------------------
// k_fold12 — layer-1/2 fold (unchanged from R11 baseline).
// ---------------------------------------------------------------------------
__global__ __launch_bounds__(128) void k_fold12(
    const float* __restrict__ x,
    const float* __restrict__ Wa1, const float* __restrict__ ba1,
    const float* __restrict__ Wb1, const float* __restrict__ bb1,
    const float* __restrict__ Wa2, const float* __restrict__ ba2,
    const float* __restrict__ Wb2, const float* __restrict__ bb2,
    float* __restrict__ norms, float* __restrict__ C2m,
    float* __restrict__ apart, unsigned int* __restrict__ ticket) {
  __shared__ float sA[128][NM2];
  __shared__ float sB[128][NM2];
  const int c = blockIdx.x;
  const int k = threadIdx.x;

  if (c < 6) {
    const int i = c*128 + k;
    const float p0 = x[3*i], p1 = x[3*i+1], p2 = x[3*i+2];
    norms[i] = sqrtf(p0*p0 + p1*p1 + p2*p2);
  }
  if (c == 6) {
    apart[k] = 0.f; apart[CCH + k] = 0.f; apart[2*CCH + k] = 0.f;
    if (k == 0) *ticket = 0u;
  }

  {
    const float A0 = Wa1[3*k], A1 = Wa1[3*k+1], A2c = Wa1[3*k+2], A3 = ba1[k];
    const float B0 = Wb1[3*k], B1 = Wb1[3*k+1], B2c = Wb1[3*k+2], B3 = bb1[k];
    const float g0 = A3*B3;              // 1
    const float g1 = A2c*B3 + A3*B2c;    // v
    const float g2 = A2c*B2c;            // v^2
    const float g3 = A1*B3 + A3*B1;      // u
    const float g4 = A1*B2c + A2c*B1;    // u v
    const float g5 = A1*B1;              // u^2
    const float g6 = A0*B3 + A3*B0;      // d
    const float g7 = A0*B2c + A2c*B0;    // d v
    const float g8 = A0*B1 + A1*B0;      // d u
    const float g9 = A0*B0;              // d^2
    const float wa = Wa2[c*CCH + k];
    const float wb = Wb2[c*CCH + k];
    sA[k][0] = wa*g0; sB[k][0] = wb*g0;
    sA[k][1] = wa*g1; sB[k][1] = wb*g1;
    sA[k][2] = wa*g2; sB[k][2] = wb*g2;
    sA[k][3] = wa*g3; sB[k][3] = wb*g3;
    sA[k][4] = wa*g4; sB[k][4] = wb*g4;
    sA[k][5] = wa*g5; sB[k][5] = wb*g5;
    sA[k][6] = wa*g6; sB[k][6] = wb*g6;
    sA[k][7] = wa*g7; sB[k][7] = wb*g7;
    sA[k][8] = wa*g8; sB[k][8] = wb*g8;
    sA[k][9] = wa*g9; sB[k][9] = wb*g9;
  }
  __syncthreads();

  for (int s = 64; s >= 1; s >>= 1) {
    if (k < s) {
      for (int t = 0; t < NM2; ++t) {
        sA[k][t] += sA[k+s][t];
        sB[k][t] += sB[k+s][t];
      }
    }
    __syncthreads();
  }
  if (k == 0) {
    sA[0][0] += ba2[c];
    sB[0][0] += bb2[c];
  }
  __syncthreads();

  if (k < 35) {
    int rem = k, a = 0;
    while (rem >= (5 - a)*(6 - a)/2) { rem -= (5 - a)*(6 - a)/2; ++a; }
    int b = 0;
    while (rem >= 5 - a - b) { rem -= 5 - a - b; ++b; }
    const int cc = rem;
    float s = 0.f;
    const int deg = a + b + cc;
    for (int a1 = 0; a1 <= a && a1 <= 2; ++a1)
      for (int b1 = 0; b1 <= b && b1 <= 2; ++b1)
        for (int c1 = 0; c1 <= cc && c1 <= 2; ++c1) {
          const int d1 = a1 + b1 + c1;
          if (d1 <= 2 && (deg - d1) <= 2)
            s += sA[0][t2i(a1, b1, c1)]
               * sB[0][t2i(a - a1, b - b1, cc - c1)];
        }
    C2m[c*NM4 + k] = s;
  }
  if (k == 35) C2m[c*NM4 + 35] = 0.f;
}

// ---------------------------------------------------------------------------
// k_pre2 (128 blocks x 64 thr): A3mT/B3mT = layer-3 fold, transposed (36x128).
// ---------------------------------------------------------------------------
__global__ void k_pre2(const float* __restrict__ Wa3, const float* __restrict__ ba3,
                       const float* __restrict__ Wb3, const float* __restrict__ bb3,
                       const float* __restrict__ C2m,
                       float* __restrict__ A3mT, float* __restrict__ B3mT) {
  const int c = blockIdx.x;
  const int j = threadIdx.x;
  if (j >= NM4) return;
  float sa = 0.f, sb = 0.f;
  if (j < 35) {
    for (int k = 0; k < CCH; ++k) {
      const float v = C2m[k*NM4 + j];
      sa += Wa3[c*CCH + k] * v;
      sb += Wb3[c*CCH + k] * v;
    }
    if (j == 0) { sa += ba3[c]; sb += bb3[c]; }
  }
  A3mT[j*CCH + c] = sa;
  B3mT[j*CCH + c] = sb;
}

// ---------------------------------------------------------------------------
// k_pre3 (768 blocks x 256): per-m u-fold of layer-3 coeffs into the 15-term
// (d,v) basis (t ordering i-major: i=0:[0..4] i=1:[5..8] i=2:[9..11]
// i=3:[12..13] i=4:[14], t15 = pad 0), then bf16x3 truncation-split, packed
// as u32 words of (k=2q lo16, k=2q+1 hi16) in exactly the MFMA B-fragment
// word layout k_main consumes. LOG2E folded into the A-poly coeffs.
// ---------------------------------------------------------------------------
__global__ __launch_bounds__(256) void k_pre3(
    const float* __restrict__ norms,
    const float* __restrict__ A3mT, const float* __restrict__ B3mT,
    unsigned int* __restrict__ WA0, unsigned int* __restrict__ WA1,
    unsigned int* __restrict__ WA2, unsigned int* __restrict__ WB0,
    unsigned int* __restrict__ WB1, unsigned int* __restrict__ WB2) {
  const int m = blockIdx.x;
  const float u = norms[m];
  float upow[5];
  upow[0] = 1.f; upow[1] = u; upow[2] = u*u;
  upow[3] = upow[2]*u; upow[4] = upow[2]*upow[2];

  for (int p = threadIdx.x; p < 8*CCH; p += 256) {
    const int q = p >> 7;     // k-pair index 0..7 (k = 2q, 2q+1)
    const int c = p & 127;
    unsigned int wa0 = 0, wa1 = 0, wa2 = 0, wb0 = 0, wb1 = 0, wb2 = 0;
    #pragma unroll
    for (int half = 0; half < 2; ++half) {
      const int t = 2*q + half;
      int rem = t, i = 0;
      while (i < 5 && rem >= 5 - i) { rem -= 5 - i; ++i; }   // decode (i=deg d, j=deg v)
      const int j = rem;
      float sa = 0.f, sb = 0.f;
      #pragma unroll
      for (int b = 0; b < 5; ++b) {
        if (i <= 4 && i + j + b <= 4) {
          const int idx = t4i(i, b, j)*CCH + c;
          sa = fmaf(A3mT[idx], upow[b], sa);
          sb = fmaf(B3mT[idx], upow[b], sb);
        }
      }
      sa *= LOG2E;
      unsigned int a0, a1, a2, b0, b1, b2;
      split3(sa, a0, a1, a2);
      split3(sb, b0, b1, b2);
      const int sh = half*16;
      wa0 |= a0 << sh; wa1 |= a1 << sh; wa2 |= a2 << sh;
      wb0 |= b0 << sh; wb1 |= b1 << sh; wb2 |= b2 << sh;
    }
    const int o = (m*8 + q)*CCH + c;
    WA0[o] = wa0; WA1[o] = wa1; WA2[o] = wa2;
    WB0[o] = wb0; WB1[o] = wb1; WB2[o] = wb2;
  }
}

// ---------------------------------------------------------------------------
// k_main (MFMA rewrite): grid (192, 6), 256 thr = 4 waves, one (m, chunk) per
// wave. Per 32-row n-tile each lane builds its 8 monomials of (d,v) for
// row = lane&31, k-slice = (lane>>5)*8+e (A layout: row=lane&31,
// k=(lane>>5)*8+e), splits them bf16x3, and contracts against the
// precomputed split B-fragments with 6 MFMAs per poly per 32-col c-tile
// (products down to 2^-18; fp32-level accuracy). C/D layout (verified):
// col=lane&31, row=(reg&3)+8*(reg>>2)+4*(lane>>5). Online log2-softmax kept
// per lane-half (16 rows each), halves merged once at the end via shfl_xor32.
// Partials interface (Mp/Sp/A0p/A1p/A2p) identical to the Horner version.
// ---------------------------------------------------------------------------
__global__ __launch_bounds__(256, 2) void k_main(
    const float* __restrict__ x, const float* __restrict__ norms,
    const unsigned int* __restrict__ WA0, const unsigned int* __restrict__ WA1,
    const unsigned int* __restrict__ WA2, const unsigned int* __restrict__ WB0,
    const unsigned int* __restrict__ WB1, const unsigned int* __restrict__ WB2,
    float* __restrict__ Mp, float* __restrict__ Sp,
    float* __restrict__ A0p, float* __restrict__ A1p, float* __restrict__ A2p) {
  __shared__ __align__(16) float4 xt[TILE];   // (x0,x1,x2, |x_n|) per n
  const int tid = threadIdx.x;
  const int wid = tid >> 6;
  const int lane = tid & 63;
  const int hl = lane >> 5;          // k-slice half
  const int ln = lane & 31;          // A row / B,C col
  const int m = blockIdx.x*4 + wid;
  const int chunk = blockIdx.y;

  if (tid < TILE) {
    const int n = chunk*TILE + tid;
    xt[tid] = make_float4(x[3*n], x[3*n+1], x[3*n+2], norms[n]);
  }

  const float u = norms[m];
  const float xm0 = x[3*m], xm1 = x[3*m+1], xm2 = x[3*m+2];
  const float uu = u*u;

  // B fragments: 4 c-tiles x {A,B poly} x 3 splits (96 VGPRs), coalesced loads.
  Frag BA0[4], BA1[4], BA2[4], BB0[4], BB1[4], BB2[4];
  #pragma unroll
  for (int ct = 0; ct < 4; ++ct) {
    #pragma unroll
    for (int p = 0; p < 4; ++p) {
      const int o = (m*8 + hl*4 + p)*CCH + ct*32 + ln;
      BA0[ct].u[p] = WA0[o]; BA1[ct].u[p] = WA1[o]; BA2[ct].u[p] = WA2[o];
      BB0[ct].u[p] = WB0[o]; BB1[ct].u[p] = WB1[o]; BB2[ct].u[p] = WB2[o];
    }
  }

  float mrun[4], srun[4], a0r[4], a1r[4], a2r[4];
  #pragma unroll
  for (int ct = 0; ct < 4; ++ct) {
    mrun[ct] = -INFINITY; srun[ct] = 0.f;
    a0r[ct] = 0.f; a1r[ct] = 0.f; a2r[ct] = 0.f;
  }

  __syncthreads();

  for (int tile = 0; tile < 4; ++tile) {
    // ---- A fragment: monomials of (d, v) for this lane's row ----
    const float4 xn = xt[tile*32 + ln];
    const float v = xn.w;
    const float dot = xm0*xn.x + xm1*xn.y + xm2*xn.z;
    const float d2 = uu + v*v - 2.f*dot;
    const float d = (d2 > 0.f) ? sqrtf(d2) : 0.f;   // grad-safe cdist semantics
    const float v2 = v*v, v3 = v2*v, v4 = v2*v2;
    const float dd = d*d, d3 = dd*d, d4 = dd*dd;
    float mono[8];
    if (hl == 0) {
      mono[0] = 1.f;   mono[1] = v;     mono[2] = v2;    mono[3] = v3;
      mono[4] = v4;    mono[5] = d;     mono[6] = d*v;   mono[7] = d*v2;
    } else {
      mono[0] = d*v3;  mono[1] = dd;    mono[2] = dd*v;  mono[3] = dd*v2;
      mono[4] = d3;    mono[5] = d3*v;  mono[6] = d4;    mono[7] = 0.f;
    }
    Frag A0f, A1f, A2f;
    #pragma unroll
    for (int p = 0; p < 4; ++p) {
      unsigned int l0, l1, l2, g0, g1, g2;
      split3(mono[2*p],   l0, l1, l2);
      split3(mono[2*p+1], g0, g1, g2);
      A0f.u[p] = l0 | (g0 << 16);
      A1f.u[p] = l1 | (g1 << 16);
      A2f.u[p] = l2 | (g2 << 16);
    }

    #pragma unroll
    for (int ct = 0; ct < 4; ++ct) {
      f32x16 accA, accB;
      #pragma unroll
      for (int r = 0; r < 16; ++r) { accA[r] = 0.f; accB[r] = 0.f; }
      // split-FMA: products ordered small -> large into the fp32 accumulator
      accA = __builtin_amdgcn_mfma_f32_32x32x16_bf16(A2f.h, BA0[ct].h, accA, 0, 0, 0);
      accA = __builtin_amdgcn_mfma_f32_32x32x16_bf16(A1f.h, BA1[ct].h, accA, 0, 0, 0);
      accA = __builtin_amdgcn_mfma_f32_32x32x16_bf16(A0f.h, BA2[ct].h, accA, 0, 0, 0);
      accA = __builtin_amdgcn_mfma_f32_32x32x16_bf16(A1f.h, BA0[ct].h, accA, 0, 0, 0);
      accA = __builtin_amdgcn_mfma_f32_32x32x16_bf16(A0f.h, BA1[ct].h, accA, 0, 0, 0);
      accA = __builtin_amdgcn_mfma_f32_32x32x16_bf16(A0f.h, BA0[ct].h, accA, 0, 0, 0);
      accB = __builtin_amdgcn_mfma_f32_32x32x16_bf16(A2f.h, BB0[ct].h, accB, 0, 0, 0);
      accB = __builtin_amdgcn_mfma_f32_32x32x16_bf16(A1f.h, BB1[ct].h, accB, 0, 0, 0);
      accB = __builtin_amdgcn_mfma_f32_32x32x16_bf16(A0f.h, BB2[ct].h, accB, 0, 0, 0);
      accB = __builtin_amdgcn_mfma_f32_32x32x16_bf16(A1f.h, BB0[ct].h, accB, 0, 0, 0);
      accB = __builtin_amdgcn_mfma_f32_32x32x16_bf16(A0f.h, BB1[ct].h, accB, 0, 0, 0);
      accB = __builtin_amdgcn_mfma_f32_32x32x16_bf16(A0f.h, BB0[ct].h, accB, 0, 0, 0);

      float hv[16];
      #pragma unroll
      for (int r = 0; r < 16; ++r) hv[r] = accA[r]*accB[r];   // logits * log2e
      float hx = hv[0];
      #pragma unroll
      for (int r = 1; r < 16; ++r) hx = fmaxf(hx, hv[r]);
      const float mnew = fmaxf(mrun[ct], hx);
      const float sc = fast_exp2(mrun[ct] - mnew);
      mrun[ct] = mnew;
      float s_ = srun[ct]*sc, A0_ = a0r[ct]*sc, A1_ = a1r[ct]*sc, A2_ = a2r[ct]*sc;
      #pragma unroll
      for (int rg = 0; rg < 4; ++rg) {
        #pragma unroll
        for (int q = 0; q < 4; ++q) {
          const float e = fast_exp2(hv[rg*4 + q] - mnew);
          const float4 xv = xt[tile*32 + rg*8 + hl*4 + q];  // row of reg rg*4+q
          s_ += e;
          A0_ = fmaf(e, xv.x, A0_);
          A1_ = fmaf(e, xv.y, A1_);
          A2_ = fmaf(e, xv.z, A2_);
        }
      }
      srun[ct] = s_; a0r[ct] = A0_; a1r[ct] = A1_; a2r[ct] = A2_;
    }
  }

  // Merge the two lane-halves' online states (each covered 64 of 128 n's).
  #pragma unroll
  for (int ct = 0; ct < 4; ++ct) {
    const float om = __shfl_xor(mrun[ct], 32);
    const float os = __shfl_xor(srun[ct], 32);
    const float o0 = __shfl_xor(a0r[ct], 32);
    const float o1 = __shfl_xor(a1r[ct], 32);
    const float o2 = __shfl_xor(a2r[ct], 32);
    const float M  = fmaxf(mrun[ct], om);
    const float e1 = fast_exp2(mrun[ct] - M);
    const float e2 = fast_exp2(om - M);
    if (hl == 0) {
      const int idx = chunk*PAIR + m*CCH + ct*32 + ln;
      Mp[idx]  = M;
      Sp[idx]  = fmaf(srun[ct], e1, os*e2);
      A0p[idx] = fmaf(a0r[ct], e1, o0*e2);
      A1p[idx] = fmaf(a1r[ct], e1, o1*e2);
      A2p[idx] = fmaf(a2r[ct], e1, o2*e2);
    }
  }
}

// ---------------------------------------------------------------------------
// k_fin (96 blocks x 256): unchanged — merge chunk partials per (m,c),
// normalize, LDS-reduce, atomics into apart; ticketed final Wf contraction.
// ---------------------------------------------------------------------------
__global__ __launch_bounds__(256) void k_fin(
    const float* __restrict__ x,
    const float* __restrict__ Mp, const float* __restrict__ Sp,
    const float* __restrict__ A0p, const float* __restrict__ A1p,
    const float* __restrict__ A2p,
    const float* __restrict__ Wf,
    float* __restrict__ apart, unsigned int* __restrict__ ticket,
    float* __restrict__ out) {
  __shared__ float red2[2][3][CCH];
  __shared__ float red[CCH][6];
  __shared__ bool last;
  const int tid = threadIdx.x;
  const int ml = tid >> 7;
  const int c = tid & 127;

  float s0 = 0.f, s1 = 0.f, s2 = 0.f;
  #pragma unroll
  for (int j = 0; j < 4; ++j) {
    const int m = blockIdx.x*8 + ml*4 + j;
    const int gid = m*CCH + c;
    float m0 = Mp[0*PAIR + gid], m1 = Mp[1*PAIR + gid], m2 = Mp[2*PAIR + gid];
    float m3 = Mp[3*PAIR + gid], m4 = Mp[4*PAIR + gid], m5 = Mp[5*PAIR + gid];
    float M = fmaxf(fmaxf(fmaxf(m0, m1), fmaxf(m2, m3)), fmaxf(m4, m5));
    float W = 0.f, g0 = 0.f, g1 = 0.f, g2 = 0.f;
    {
      const float e0 = fast_exp2(m0 - M), e1 = fast_exp2(m1 - M);
      const float e2 = fast_exp2(m2 - M), e3 = fast_exp2(m3 - M);
      const float e4 = fast_exp2(m4 - M), e5 = fast_exp2(m5 - M);
      W = Sp[0*PAIR+gid]*e0 + Sp[1*PAIR+gid]*e1 + Sp[2*PAIR+gid]*e2
        + Sp[3*PAIR+gid]*e3 + Sp[4*PAIR+gid]*e4 + Sp[5*PAIR+gid]*e5;
      g0 = A0p[0*PAIR+gid]*e0 + A0p[1*PAIR+gid]*e1 + A0p[2*PAIR+gid]*e2
         + A0p[3*PAIR+gid]*e3 + A0p[4*PAIR+gid]*e4 + A0p[5*PAIR+gid]*e5;
      g1 = A1p[0*PAIR+gid]*e0 + A1p[1*PAIR+gid]*e1 + A1p[2*PAIR+gid]*e2
         + A1p[3*PAIR+gid]*e3 + A1p[4*PAIR+gid]*e4 + A1p[5*PAIR+gid]*e5;
      g2 = A2p[0*PAIR+gid]*e0 + A2p[1*PAIR+gid]*e1 + A2p[2*PAIR+gid]*e2
         + A2p[3*PAIR+gid]*e3 + A2p[4*PAIR+gid]*e4 + A2p[5*PAIR+gid]*e5;
    }
    const float inv = 1.f / W;
    s0 = fmaf(g0, inv, s0);
    s1 = fmaf(g1, inv, s1);
    s2 = fmaf(g2, inv, s2);
  }
  red2[ml][0][c] = s0; red2[ml][1][c] = s1; red2[ml][2][c] = s2;
  __syncthreads();
  for (int p = tid; p < NACC; p += 256) {
    const int i = p >> 7, cc = p & 127;
    atomicAdd(&apart[p], red2[0][i][cc] + red2[1][i][cc]);
  }
  __threadfence();
  __syncthreads();
  if (tid == 0) {
    const unsigned int old = atomicAdd(ticket, 1u);
    last = (old == FINB - 1);
  }
  __syncthreads();
  if (!last) return;
  __threadfence();

  if (tid < CCH) {
    const int cc = tid;
    const float a0 = __hip_atomic_load(&apart[cc],          __ATOMIC_RELAXED, __HIP_MEMORY_SCOPE_AGENT);
    const float a1 = __hip_atomic_load(&apart[CCH + cc],    __ATOMIC_RELAXED, __HIP_MEMORY_SCOPE_AGENT);
    const float a2 = __hip_atomic_load(&apart[2*CCH + cc],  __ATOMIC_RELAXED, __HIP_MEMORY_SCOPE_AGENT);
    const float w0 = Wf[cc], w1 = Wf[CCH + cc];
    red[cc][0] = w0*a0; red[cc][1] = w0*a1; red[cc][2] = w0*a2;
    red[cc][3] = w1*a0; red[cc][4] = w1*a1; red[cc][5] = w1*a2;
  }
  __syncthreads();
  if (tid < 6) {
    float s = 0.f;
    for (int k = 0; k < CCH; ++k) s += red[k][tid];
    out[3 + tid] = s;
  }
  if (tid < 3) out[tid] = x[tid];
}

// ---------------------------------------------------------------------------
extern "C" void kernel_launch(void* const* d_in, const int* in_sizes, int n_in,
                              void* d_out, int out_size, void* d_ws, size_t ws_size,
                              hipStream_t stream) {
  const float* x   = (const float*)d_in[0];
  const float* Wa1 = (const float*)d_in[1];
  const float* ba1 = (const float*)d_in[2];
  const float* Wb1 = (const float*)d_in[3];
  const float* bb1 = (const float*)d_in[4];
  const float* Wa2 = (const float*)d_in[5];
  const float* ba2 = (const float*)d_in[6];
  const float* Wb2 = (const float*)d_in[7];
  const float* bb2 = (const float*)d_in[8];
  const float* Wa3 = (const float*)d_in[9];
  const float* ba3 = (const float*)d_in[10];
  const float* Wb3 = (const float*)d_in[11];
  const float* bb3 = (const float*)d_in[12];
  const float* Wf  = (const float*)d_in[13];
  float* out = (float*)d_out;

  float* ws     = (float*)d_ws;
  float* norms  = ws;                      // 768
  float* C2m    = norms + NPTS;            // 128*36
  float* A3mT   = C2m   + CCH*NM4;         // 36*128
  float* B3mT   = A3mT  + NM4*CCH;         // 36*128
  float* Mp     = B3mT  + NM4*CCH;         // 6*98304
  float* Sp     = Mp    + NCHUNK*PAIR;
  float* A0p    = Sp    + NCHUNK*PAIR;
  float* A1p    = A0p   + NCHUNK*PAIR;
  float* A2p    = A1p   + NCHUNK*PAIR;
  float* apart  = A2p   + NCHUNK*PAIR;     // 384
  unsigned int* ticket = (unsigned int*)(apart + NACC);

  // split-coefficient planes (6 x 3 MB), 256B-aligned after ticket
  size_t off = (((size_t)((char*)(ticket + 1) - (char*)d_ws)) + 255) & ~(size_t)255;
  unsigned int* WA0 = (unsigned int*)((char*)d_ws + off);
  unsigned int* WA1 = WA0 + NQW;
  unsigned int* WA2 = WA1 + NQW;
  unsigned int* WB0 = WA2 + NQW;
  unsigned int* WB1 = WB0 + NQW;
  unsigned int* WB2 = WB1 + NQW;

  hipLaunchKernelGGL(k_fold12, dim3(CCH), dim3(128), 0, stream,
                     x, Wa1, ba1, Wb1, bb1, Wa2, ba2, Wb2, bb2,
                     norms, C2m, apart, ticket);
  hipLaunchKernelGGL(k_pre2, dim3(CCH), dim3(64), 0, stream,
                     Wa3, ba3, Wb3, bb3, C2m, A3mT, B3mT);
  hipLaunchKernelGGL(k_pre3, dim3(NPTS), dim3(256), 0, stream,
                     norms, A3mT, B3mT, WA0, WA1, WA2, WB0, WB1, WB2);
  hipLaunchKernelGGL(k_main, dim3(NPTS/4, NCHUNK), dim3(256), 0, stream,
                     x, norms, WA0, WA1, WA2, WB0, WB1, WB2,
                     Mp, Sp, A0p, A1p, A2p);
  hipLaunchKernelGGL(k_fin, dim3(FINB), dim3(256), 0, stream,
                     x, Mp, Sp, A0p, A1p, A2p, Wf, apart, ticket, out);
}

// Round 2
// 155.691 us; speedup vs baseline: 1.1060x; 1.1060x over previous
//
#include <hip/hip_runtime.h>

#define NPTS 768
#define CCH  128
#define NM4  36    // 35 deg<=4 monomials in (d,u,v) + 1 pad
#define NM2  10    // deg<=2 monomials
#define NCHUNK 2   // n-chunks (384 n's each)
#define CTILE (NPTS/NCHUNK)   // 384 n per chunk
#define PAIR (NPTS*CCH)
#define NACC 384   // apart accumulator size (3 x 128)
#define FINB 96    // k_fin grid
#define LOG2E 1.4426950408889634f

typedef __attribute__((ext_vector_type(8))) short bf16x8;   // 8 bf16 in 4 VGPRs
typedef __attribute__((ext_vector_type(16))) float f32x16;  // MFMA 32x32 acc
union Frag { unsigned int u[4]; bf16x8 h; };

__device__ __forceinline__ float fast_exp2(float x) {
  return __builtin_amdgcn_exp2f(x);   // v_exp_f32 (base-2)
}

// Truncation-based 3-way bf16 split: x = h0 + h1 + h2 + eps, |eps| <= 2^-27 |x|.
__device__ __forceinline__ void split3(float x, unsigned int& h0,
                                       unsigned int& h1, unsigned int& h2) {
  const unsigned int b0 = __float_as_uint(x);
  h0 = b0 >> 16;
  const float r1 = x - __uint_as_float(b0 & 0xFFFF0000u);
  const unsigned int b1 = __float_as_uint(r1);
  h1 = b1 >> 16;
  const float r2 = r1 - __uint_as_float(b1 & 0xFFFF0000u);
  h2 = __float_as_uint(r2) >> 16;
}

// ---- monomial index helpers ------------------------------------------------
// (a,b,c) = (deg d, deg u, deg v), a outermost. Runtime-safe (indexes global
// memory only, never private arrays).
__device__ __forceinline__ int t4i(int a, int b, int c) {
  int t = 0;
  for (int aa = 0; aa < a; ++aa) t += (5 - aa) * (6 - aa) / 2;
  for (int bb = 0; bb < b; ++bb) t += (5 - a - bb);
  return t + c;
}
__device__ __forceinline__ int t2i(int a, int b, int c) {
  int t = 0;
  for (int aa = 0; aa < a; ++aa) t += (3 - aa) * (4 - aa) / 2;
  for (int bb = 0; bb < b; ++bb) t += (3 - a - bb);
  return t + c;
}

// ---------------------------------------------------------------------------
// k_fold12 — layer-1/2 fold (unchanged).
// ---------------------------------------------------------------------------
__global__ __launch_bounds__(128) void k_fold12(
    const float* __restrict__ x,
    const float* __restrict__ Wa1, const float* __restrict__ ba1,
    const float* __restrict__ Wb1, const float* __restrict__ bb1,
    const float* __restrict__ Wa2, const float* __restrict__ ba2,
    const float* __restrict__ Wb2, const float* __restrict__ bb2,
    float* __restrict__ norms, float* __restrict__ C2m,
    float* __restrict__ apart, unsigned int* __restrict__ ticket) {
  __shared__ float sA[128][NM2];
  __shared__ float sB[128][NM2];
  const int c = blockIdx.x;
  const int k = threadIdx.x;

  if (c < 6) {
    const int i = c*128 + k;
    const float p0 = x[3*i], p1 = x[3*i+1], p2 = x[3*i+2];
    norms[i] = sqrtf(p0*p0 + p1*p1 + p2*p2);
  }
  if (c == 6) {
    apart[k] = 0.f; apart[CCH + k] = 0.f; apart[2*CCH + k] = 0.f;
    if (k == 0) *ticket = 0u;
  }

  {
    const float A0 = Wa1[3*k], A1 = Wa1[3*k+1], A2c = Wa1[3*k+2], A3 = ba1[k];
    const float B0 = Wb1[3*k], B1 = Wb1[3*k+1], B2c = Wb1[3*k+2], B3 = bb1[k];
    const float g0 = A3*B3;              // 1
    const float g1 = A2c*B3 + A3*B2c;    // v
    const float g2 = A2c*B2c;            // v^2
    const float g3 = A1*B3 + A3*B1;      // u
    const float g4 = A1*B2c + A2c*B1;    // u v
    const float g5 = A1*B1;              // u^2
    const float g6 = A0*B3 + A3*B0;      // d
    const float g7 = A0*B2c + A2c*B0;    // d v
    const float g8 = A0*B1 + A1*B0;      // d u
    const float g9 = A0*B0;              // d^2
    const float wa = Wa2[c*CCH + k];
    const float wb = Wb2[c*CCH + k];
    sA[k][0] = wa*g0; sB[k][0] = wb*g0;
    sA[k][1] = wa*g1; sB[k][1] = wb*g1;
    sA[k][2] = wa*g2; sB[k][2] = wb*g2;
    sA[k][3] = wa*g3; sB[k][3] = wb*g3;
    sA[k][4] = wa*g4; sB[k][4] = wb*g4;
    sA[k][5] = wa*g5; sB[k][5] = wb*g5;
    sA[k][6] = wa*g6; sB[k][6] = wb*g6;
    sA[k][7] = wa*g7; sB[k][7] = wb*g7;
    sA[k][8] = wa*g8; sB[k][8] = wb*g8;
    sA[k][9] = wa*g9; sB[k][9] = wb*g9;
  }
  __syncthreads();

  for (int s = 64; s >= 1; s >>= 1) {
    if (k < s) {
      for (int t = 0; t < NM2; ++t) {
        sA[k][t] += sA[k+s][t];
        sB[k][t] += sB[k+s][t];
      }
    }
    __syncthreads();
  }
  if (k == 0) {
    sA[0][0] += ba2[c];
    sB[0][0] += bb2[c];
  }
  __syncthreads();

  if (k < 35) {
    int rem = k, a = 0;
    while (rem >= (5 - a)*(6 - a)/2) { rem -= (5 - a)*(6 - a)/2; ++a; }
    int b = 0;
    while (rem >= 5 - a - b) { rem -= 5 - a - b; ++b; }
    const int cc = rem;
    float s = 0.f;
    const int deg = a + b + cc;
    for (int a1 = 0; a1 <= a && a1 <= 2; ++a1)
      for (int b1 = 0; b1 <= b && b1 <= 2; ++b1)
        for (int c1 = 0; c1 <= cc && c1 <= 2; ++c1) {
          const int d1 = a1 + b1 + c1;
          if (d1 <= 2 && (deg - d1) <= 2)
            s += sA[0][t2i(a1, b1, c1)]
               * sB[0][t2i(a - a1, b - b1, cc - c1)];
        }
    C2m[c*NM4 + k] = s;
  }
  if (k == 35) C2m[c*NM4 + 35] = 0.f;
}

// ---------------------------------------------------------------------------
// k_pre2 (128 blocks x 64 thr): A3mT/B3mT = layer-3 fold, transposed (36x128).
// ---------------------------------------------------------------------------
__global__ void k_pre2(const float* __restrict__ Wa3, const float* __restrict__ ba3,
                       const float* __restrict__ Wb3, const float* __restrict__ bb3,
                       const float* __restrict__ C2m,
                       float* __restrict__ A3mT, float* __restrict__ B3mT) {
  const int c = blockIdx.x;
  const int j = threadIdx.x;
  if (j >= NM4) return;
  float sa = 0.f, sb = 0.f;
  if (j < 35) {
    for (int k = 0; k < CCH; ++k) {
      const float v = C2m[k*NM4 + j];
      sa += Wa3[c*CCH + k] * v;
      sb += Wb3[c*CCH + k] * v;
    }
    if (j == 0) { sa += ba3[c]; sb += bb3[c]; }
  }
  A3mT[j*CCH + c] = sa;
  B3mT[j*CCH + c] = sb;
}

// ---------------------------------------------------------------------------
// k_main (v2): grid (768, 2), 256 thr = 4 waves. Block owns one m; wave owns
// one 32-col c-tile (ct = wid). B-fragments (u-folded layer-3 coeffs in the
// 15-term (d,v) basis, t ordering i-major, t15 pad) are computed IN-REGISTER
// per wave from the L2-resident A3mT/B3mT (36x128) tables: ~44 coalesced
// loads + fma + 16 split3 per lane, once per wave. No coefficient planes in
// HBM, no k_pre3, live fragment set = 6 Frags (24 VGPRs) — R1's 96-VGPR
// spill storm eliminated. Per 32-row n-tile: lane builds its 8 monomials of
// (d,v) (A layout: row=lane&31, k=(lane>>5)*8+e, pairs packed lo/hi),
// split3, 6 MFMAs per poly (products >= 2^-18 kept; fp32-level error).
// C/D layout (verified R1): col=lane&31, row=(reg&3)+8*(reg>>2)+4*(lane>>5).
// Online log2-softmax per lane-half; halves merged via shfl_xor(32).
// ---------------------------------------------------------------------------
__global__ __launch_bounds__(256, 4) void k_main(
    const float* __restrict__ x, const float* __restrict__ norms,
    const float* __restrict__ A3mT, const float* __restrict__ B3mT,
    float* __restrict__ Mp, float* __restrict__ Sp,
    float* __restrict__ A0p, float* __restrict__ A1p, float* __restrict__ A2p) {
  __shared__ __align__(16) float4 xt[CTILE];   // (x0,x1,x2,|x_n|), 6 KB
  const int tid = threadIdx.x;
  const int wid = tid >> 6;          // c-tile index 0..3
  const int lane = tid & 63;
  const int hl = lane >> 5;          // k-slice half
  const int ln = lane & 31;          // A row / B,C col
  const int m = blockIdx.x;
  const int chunk = blockIdx.y;
  const int c = wid*32 + ln;         // this lane's channel column

  // Stage this chunk's 384 n's (x, |x|) into LDS.
  for (int p = tid; p < CTILE; p += 256) {
    const int n = chunk*CTILE + p;
    xt[p] = make_float4(x[3*n], x[3*n+1], x[3*n+2], norms[n]);
  }

  const float u = norms[m];
  const float xm0 = x[3*m], xm1 = x[3*m+1], xm2 = x[3*m+2];
  const float uu = u*u;
  const float up[5] = {1.f, u, uu, uu*u, uu*uu};   // static-indexed only

  // ---- B-fragments: fold u, scale A-poly by log2e, split3, MFMA-pack ----
  // word p of half hl holds t = 8*hl + 2*p (lo16) and +1 (hi16).
  Frag ba0, ba1, ba2, bb0, bb1, bb2;
  #pragma unroll
  for (int p = 0; p < 4; ++p) {
    unsigned int wa0 = 0, wa1 = 0, wa2 = 0, wb0 = 0, wb1 = 0, wb2 = 0;
    #pragma unroll
    for (int half = 0; half < 2; ++half) {
      const int t = 8*hl + 2*p + half;
      int rem = t, i = 0;
      while (i < 5 && rem >= 5 - i) { rem -= 5 - i; ++i; }  // t=15 -> i=5 (pad)
      const int j = rem;
      float sa = 0.f, sb = 0.f;
      #pragma unroll
      for (int b = 0; b < 5; ++b) {
        if (i + j + b <= 4) {            // i=5 (pad) never enters
          const int idx = t4i(i, b, j)*CCH + c;
          sa = fmaf(A3mT[idx], up[b], sa);
          sb = fmaf(B3mT[idx], up[b], sb);
        }
      }
      sa *= LOG2E;
      unsigned int a0, a1, a2, b0, b1, b2;
      split3(sa, a0, a1, a2);
      split3(sb, b0, b1, b2);
      const int sh = half*16;
      wa0 |= a0 << sh; wa1 |= a1 << sh; wa2 |= a2 << sh;
      wb0 |= b0 << sh; wb1 |= b1 << sh; wb2 |= b2 << sh;
    }
    ba0.u[p] = wa0; ba1.u[p] = wa1; ba2.u[p] = wa2;
    bb0.u[p] = wb0; bb1.u[p] = wb1; bb2.u[p] = wb2;
  }

  __syncthreads();

  float mrun = -INFINITY, srun = 0.f, a0r = 0.f, a1r = 0.f, a2r = 0.f;

  for (int tile = 0; tile < CTILE/32; ++tile) {
    // ---- A fragment: monomials of (d, v) for this lane's row ----
    const float4 xn = xt[tile*32 + ln];
    const float v = xn.w;
    const float dot = xm0*xn.x + xm1*xn.y + xm2*xn.z;
    const float d2 = uu + v*v - 2.f*dot;
    const float d = (d2 > 0.f) ? sqrtf(d2) : 0.f;   // grad-safe cdist semantics
    const float v2 = v*v, v3 = v2*v, v4 = v2*v2;
    const float dd = d*d, d3 = dd*d, d4 = dd*dd;
    float mono[8];
    if (hl == 0) {
      mono[0] = 1.f;   mono[1] = v;     mono[2] = v2;    mono[3] = v3;
      mono[4] = v4;    mono[5] = d;     mono[6] = d*v;   mono[7] = d*v2;
    } else {
      mono[0] = d*v3;  mono[1] = dd;    mono[2] = dd*v;  mono[3] = dd*v2;
      mono[4] = d3;    mono[5] = d3*v;  mono[6] = d4;    mono[7] = 0.f;
    }
    Frag A0f, A1f, A2f;
    #pragma unroll
    for (int p = 0; p < 4; ++p) {
      unsigned int l0, l1, l2, g0, g1, g2;
      split3(mono[2*p],   l0, l1, l2);
      split3(mono[2*p+1], g0, g1, g2);
      A0f.u[p] = l0 | (g0 << 16);
      A1f.u[p] = l1 | (g1 << 16);
      A2f.u[p] = l2 | (g2 << 16);
    }

    f32x16 accA, accB;
    #pragma unroll
    for (int r = 0; r < 16; ++r) { accA[r] = 0.f; accB[r] = 0.f; }
    // split-FMA: the 6 products of combined magnitude >= 2^-18
    accA = __builtin_amdgcn_mfma_f32_32x32x16_bf16(A2f.h, ba0.h, accA, 0, 0, 0);
    accA = __builtin_amdgcn_mfma_f32_32x32x16_bf16(A1f.h, ba1.h, accA, 0, 0, 0);
    accA = __builtin_amdgcn_mfma_f32_32x32x16_bf16(A0f.h, ba2.h, accA, 0, 0, 0);
    accA = __builtin_amdgcn_mfma_f32_32x32x16_bf16(A1f.h, ba0.h, accA, 0, 0, 0);
    accA = __builtin_amdgcn_mfma_f32_32x32x16_bf16(A0f.h, ba1.h, accA, 0, 0, 0);
    accA = __builtin_amdgcn_mfma_f32_32x32x16_bf16(A0f.h, ba0.h, accA, 0, 0, 0);
    accB = __builtin_amdgcn_mfma_f32_32x32x16_bf16(A2f.h, bb0.h, accB, 0, 0, 0);
    accB = __builtin_amdgcn_mfma_f32_32x32x16_bf16(A1f.h, bb1.h, accB, 0, 0, 0);
    accB = __builtin_amdgcn_mfma_f32_32x32x16_bf16(A0f.h, bb2.h, accB, 0, 0, 0);
    accB = __builtin_amdgcn_mfma_f32_32x32x16_bf16(A1f.h, bb0.h, accB, 0, 0, 0);
    accB = __builtin_amdgcn_mfma_f32_32x32x16_bf16(A0f.h, bb1.h, accB, 0, 0, 0);
    accB = __builtin_amdgcn_mfma_f32_32x32x16_bf16(A0f.h, bb0.h, accB, 0, 0, 0);

    float hv[16];
    #pragma unroll
    for (int r = 0; r < 16; ++r) hv[r] = accA[r]*accB[r];   // logits * log2e
    float hx = hv[0];
    #pragma unroll
    for (int r = 1; r < 16; ++r) hx = fmaxf(hx, hv[r]);
    const float mnew = fmaxf(mrun, hx);
    const float sc = fast_exp2(mrun - mnew);
    mrun = mnew;
    float s_ = srun*sc, A0_ = a0r*sc, A1_ = a1r*sc, A2_ = a2r*sc;
    #pragma unroll
    for (int rg = 0; rg < 4; ++rg) {
      #pragma unroll
      for (int q = 0; q < 4; ++q) {
        const float e = fast_exp2(hv[rg*4 + q] - mnew);
        const float4 xv = xt[tile*32 + rg*8 + hl*4 + q];  // row of reg rg*4+q
        s_ += e;
        A0_ = fmaf(e, xv.x, A0_);
        A1_ = fmaf(e, xv.y, A1_);
        A2_ = fmaf(e, xv.z, A2_);
      }
    }
    srun = s_; a0r = A0_; a1r = A1_; a2r = A2_;
  }

  // Merge the two lane-halves' online states (each covered half the rows).
  {
    const float om = __shfl_xor(mrun, 32);
    const float os = __shfl_xor(srun, 32);
    const float o0 = __shfl_xor(a0r, 32);
    const float o1 = __shfl_xor(a1r, 32);
    const float o2 = __shfl_xor(a2r, 32);
    const float M  = fmaxf(mrun, om);
    const float e1 = fast_exp2(mrun - M);
    const float e2 = fast_exp2(om - M);
    if (hl == 0) {
      const int idx = chunk*PAIR + m*CCH + c;
      Mp[idx]  = M;
      Sp[idx]  = fmaf(srun, e1, os*e2);
      A0p[idx] = fmaf(a0r, e1, o0*e2);
      A1p[idx] = fmaf(a1r, e1, o1*e2);
      A2p[idx] = fmaf(a2r, e1, o2*e2);
    }
  }
}

// ---------------------------------------------------------------------------
// k_fin (96 blocks x 256): merge NCHUNK=2 partials per (m,c), normalize,
// LDS-reduce 8 m-rows, atomics into apart; ticketed Wf contraction + out.
// ---------------------------------------------------------------------------
__global__ __launch_bounds__(256) void k_fin(
    const float* __restrict__ x,
    const float* __restrict__ Mp, const float* __restrict__ Sp,
    const float* __restrict__ A0p, const float* __restrict__ A1p,
    const float* __restrict__ A2p,
    const float* __restrict__ Wf,
    float* __restrict__ apart, unsigned int* __restrict__ ticket,
    float* __restrict__ out) {
  __shared__ float red2[2][3][CCH];
  __shared__ float red[CCH][6];
  __shared__ bool last;
  const int tid = threadIdx.x;
  const int ml = tid >> 7;
  const int c = tid & 127;

  float s0 = 0.f, s1 = 0.f, s2 = 0.f;
  #pragma unroll
  for (int j = 0; j < 4; ++j) {
    const int m = blockIdx.x*8 + ml*4 + j;
    const int gid = m*CCH + c;
    const float m0 = Mp[0*PAIR + gid], m1 = Mp[1*PAIR + gid];
    const float M = fmaxf(m0, m1);
    const float e0 = fast_exp2(m0 - M), e1 = fast_exp2(m1 - M);
    const float W  = Sp[0*PAIR+gid]*e0 + Sp[1*PAIR+gid]*e1;
    const float g0 = A0p[0*PAIR+gid]*e0 + A0p[1*PAIR+gid]*e1;
    const float g1 = A1p[0*PAIR+gid]*e0 + A1p[1*PAIR+gid]*e1;
    const float g2 = A2p[0*PAIR+gid]*e0 + A2p[1*PAIR+gid]*e1;
    const float inv = 1.f / W;
    s0 = fmaf(g0, inv, s0);
    s1 = fmaf(g1, inv, s1);
    s2 = fmaf(g2, inv, s2);
  }
  red2[ml][0][c] = s0; red2[ml][1][c] = s1; red2[ml][2][c] = s2;
  __syncthreads();
  for (int p = tid; p < NACC; p += 256) {
    const int i = p >> 7, cc = p & 127;
    atomicAdd(&apart[p], red2[0][i][cc] + red2[1][i][cc]);
  }
  __threadfence();
  __syncthreads();
  if (tid == 0) {
    const unsigned int old = atomicAdd(ticket, 1u);
    last = (old == FINB - 1);
  }
  __syncthreads();
  if (!last) return;
  __threadfence();

  if (tid < CCH) {
    const int cc = tid;
    const float a0 = __hip_atomic_load(&apart[cc],          __ATOMIC_RELAXED, __HIP_MEMORY_SCOPE_AGENT);
    const float a1 = __hip_atomic_load(&apart[CCH + cc],    __ATOMIC_RELAXED, __HIP_MEMORY_SCOPE_AGENT);
    const float a2 = __hip_atomic_load(&apart[2*CCH + cc],  __ATOMIC_RELAXED, __HIP_MEMORY_SCOPE_AGENT);
    const float w0 = Wf[cc], w1 = Wf[CCH + cc];
    red[cc][0] = w0*a0; red[cc][1] = w0*a1; red[cc][2] = w0*a2;
    red[cc][3] = w1*a0; red[cc][4] = w1*a1; red[cc][5] = w1*a2;
  }
  __syncthreads();
  if (tid < 6) {
    float s = 0.f;
    for (int k = 0; k < CCH; ++k) s += red[k][tid];
    out[3 + tid] = s;
  }
  if (tid < 3) out[tid] = x[tid];
}

// ---------------------------------------------------------------------------
extern "C" void kernel_launch(void* const* d_in, const int* in_sizes, int n_in,
                              void* d_out, int out_size, void* d_ws, size_t ws_size,
                              hipStream_t stream) {
  const float* x   = (const float*)d_in[0];
  const float* Wa1 = (const float*)d_in[1];
  const float* ba1 = (const float*)d_in[2];
  const float* Wb1 = (const float*)d_in[3];
  const float* bb1 = (const float*)d_in[4];
  const float* Wa2 = (const float*)d_in[5];
  const float* ba2 = (const float*)d_in[6];
  const float* Wb2 = (const float*)d_in[7];
  const float* bb2 = (const float*)d_in[8];
  const float* Wa3 = (const float*)d_in[9];
  const float* ba3 = (const float*)d_in[10];
  const float* Wb3 = (const float*)d_in[11];
  const float* bb3 = (const float*)d_in[12];
  const float* Wf  = (const float*)d_in[13];
  float* out = (float*)d_out;

  float* ws     = (float*)d_ws;
  float* norms  = ws;                      // 768
  float* C2m    = norms + NPTS;            // 128*36
  float* A3mT   = C2m   + CCH*NM4;         // 36*128
  float* B3mT   = A3mT  + NM4*CCH;         // 36*128
  float* Mp     = B3mT  + NM4*CCH;         // 2*98304
  float* Sp     = Mp    + NCHUNK*PAIR;
  float* A0p    = Sp    + NCHUNK*PAIR;
  float* A1p    = A0p   + NCHUNK*PAIR;
  float* A2p    = A1p   + NCHUNK*PAIR;
  float* apart  = A2p   + NCHUNK*PAIR;     // 384
  unsigned int* ticket = (unsigned int*)(apart + NACC);

  hipLaunchKernelGGL(k_fold12, dim3(CCH), dim3(128), 0, stream,
                     x, Wa1, ba1, Wb1, bb1, Wa2, ba2, Wb2, bb2,
                     norms, C2m, apart, ticket);
  hipLaunchKernelGGL(k_pre2, dim3(CCH), dim3(64), 0, stream,
                     Wa3, ba3, Wb3, bb3, C2m, A3mT, B3mT);
  hipLaunchKernelGGL(k_main, dim3(NPTS, NCHUNK), dim3(256), 0, stream,
                     x, norms, A3mT, B3mT, Mp, Sp, A0p, A1p, A2p);
  hipLaunchKernelGGL(k_fin, dim3(FINB), dim3(256), 0, stream,
                     x, Mp, Sp, A0p, A1p, A2p, Wf, apart, ticket, out);
}